// Round 4
// baseline (135.894 us; speedup 1.0000x reference)
//
#include <hip/hip_runtime.h>
#include <math.h>

#define S_LEN 2048
#define DMODEL 1024
#define NHEAD 16
#define DHEAD 64
#define WIN 128
#define NQKV 1152

typedef _Float16 f16x8 __attribute__((ext_vector_type(8)));
typedef float f32x4 __attribute__((ext_vector_type(4)));

__device__ __forceinline__ ushort f2h(float f) {
  union { _Float16 h; ushort u; } v; v.h = (_Float16)f; return v.u;
}
__device__ __forceinline__ f16x8 cvt8(float4 a, float4 b) {
  f16x8 r;
  r[0] = (_Float16)a.x; r[1] = (_Float16)a.y; r[2] = (_Float16)a.z; r[3] = (_Float16)a.w;
  r[4] = (_Float16)b.x; r[5] = (_Float16)b.y; r[6] = (_Float16)b.z; r[7] = (_Float16)b.w;
  return r;
}

typedef __attribute__((address_space(1))) const unsigned GU;
typedef __attribute__((address_space(3))) unsigned LU;
__device__ __forceinline__ void async16(const ushort* g, ushort* l) {
  __builtin_amdgcn_global_load_lds((GU*)g, (LU*)l, 16, 0, 0);
}

// ---------------------------------------------------------------- fused GEMM (64x128 tile, dbuf reg-prefetch)
// MODE 1: A=x fp32[2048x1024], B=Wqkv fp32[1152x1024]; epilogue -> k16/vT/q16 f16 (q cols x8).
//         blocks [GEMM_BLKS, GEMM_BLKS+64): convert Wout fp32 -> wo16 f16.
// MODE 0: A=obuf f16[2048x1024], B=wo16 f16[1024x1024]; epilogue -> out fp32 + bias.
template<int MODE>
__global__ __launch_bounds__(256)
void gemm_fused(const float* __restrict__ Af, const float* __restrict__ Bf,
                const ushort* __restrict__ Ah, const ushort* __restrict__ Bh,
                const float* __restrict__ bias, float* __restrict__ Cout,
                ushort* __restrict__ k16, ushort* __restrict__ vT, ushort* __restrict__ q16,
                const float* __restrict__ Wout, ushort* __restrict__ wo16,
                int NTILES) {
  const int bid = blockIdx.x;
  const int t = threadIdx.x;

  if (MODE == 1 && bid >= NTILES) {  // ---- Wout convert side-job
    const float4* src = (const float4*)Wout;
    ushort4* dst = (ushort4*)wo16;
    int i = (bid - NTILES) * 256 + t;
#pragma unroll
    for (int it = 0; it < 16; ++it, i += 16384) {
      const float4 v = src[i];
      ushort4 h; h.x = f2h(v.x); h.y = f2h(v.y); h.z = f2h(v.z); h.w = f2h(v.w);
      dst[i] = h;
    }
    return;
  }

  __shared__ __align__(16) ushort sA[2][64 * 32];
  __shared__ __align__(16) ushort sB[2][128 * 32];

  const int lane = t & 63, w = t >> 6;
  const int quad = lane >> 4, l16 = lane & 15;
  const int wm = (w & 1) * 32, wn = (w >> 1) * 64;
  const int m0 = (bid & 31) * 64, n0 = (bid >> 5) * 128;
  const int rowA = t >> 2, kc = (t & 3) * 8;
  const int K = 1024;

  f32x4 acc[2][4] = {};

  // prefetch register sets (dist-2)
  float4 pa[2][2], pb[2][4];
  uint4 qa[2], qb[2][2];

  const float*  Af0 = Af + (size_t)(m0 + rowA) * K + kc;
  const float*  Bf0 = Bf + (size_t)(n0 + rowA) * K + kc;
  const float*  Bf1 = Bf0 + (size_t)64 * K;
  const ushort* Ah0 = Ah + (size_t)(m0 + rowA) * K + kc;
  const ushort* Bh0 = Bh + (size_t)(n0 + rowA) * K + kc;
  const ushort* Bh1 = Bh0 + (size_t)64 * K;

#define LOADS(s, ks)                                                        \
  do {                                                                      \
    const int off = (ks) * 32;                                              \
    if (MODE == 1) {                                                        \
      pa[s][0] = *(const float4*)(Af0 + off);                               \
      pa[s][1] = *(const float4*)(Af0 + off + 4);                           \
      pb[s][0] = *(const float4*)(Bf0 + off);                               \
      pb[s][1] = *(const float4*)(Bf0 + off + 4);                           \
      pb[s][2] = *(const float4*)(Bf1 + off);                               \
      pb[s][3] = *(const float4*)(Bf1 + off + 4);                           \
    } else {                                                                \
      qa[s]    = *(const uint4*)(Ah0 + off);                                \
      qb[s][0] = *(const uint4*)(Bh0 + off);                                \
      qb[s][1] = *(const uint4*)(Bh1 + off);                                \
    }                                                                       \
  } while (0)

#define STORES(s, p)                                                        \
  do {                                                                      \
    if (MODE == 1) {                                                        \
      *(f16x8*)(&sA[p][rowA * 32 + kc])        = cvt8(pa[s][0], pa[s][1]);  \
      *(f16x8*)(&sB[p][rowA * 32 + kc])        = cvt8(pb[s][0], pb[s][1]);  \
      *(f16x8*)(&sB[p][(rowA + 64) * 32 + kc]) = cvt8(pb[s][2], pb[s][3]);  \
    } else {                                                                \
      *(uint4*)(&sA[p][rowA * 32 + kc])        = qa[s];                     \
      *(uint4*)(&sB[p][rowA * 32 + kc])        = qb[s][0];                  \
      *(uint4*)(&sB[p][(rowA + 64) * 32 + kc]) = qb[s][1];                  \
    }                                                                       \
  } while (0)

#define MFMAS(p)                                                            \
  do {                                                                      \
    f16x8 af[2], bf[4];                                                     \
    _Pragma("unroll") for (int i = 0; i < 2; ++i)                           \
        af[i] = *(const f16x8*)(&sA[p][(wm + 16 * i + l16) * 32 + quad * 8]); \
    _Pragma("unroll") for (int j = 0; j < 4; ++j)                           \
        bf[j] = *(const f16x8*)(&sB[p][(wn + 16 * j + l16) * 32 + quad * 8]); \
    _Pragma("unroll") for (int i = 0; i < 2; ++i)                           \
      _Pragma("unroll") for (int j = 0; j < 4; ++j)                         \
        acc[i][j] = __builtin_amdgcn_mfma_f32_16x16x32_f16(af[i], bf[j], acc[i][j], 0, 0, 0); \
  } while (0)

  LOADS(0, 0);
  LOADS(1, 1);
  STORES(0, 0);
  __syncthreads();
  for (int ks = 0; ks < 32; ks += 2) {
    if (ks + 2 < 32) LOADS(0, ks + 2);
    MFMAS(0);
    STORES(1, 1);
    __syncthreads();
    if (ks + 3 < 32) LOADS(1, ks + 3);
    MFMAS(1);
    if (ks + 2 < 32) STORES(0, 0);
    __syncthreads();
  }

  // ---- epilogue
#pragma unroll
  for (int i = 0; i < 2; ++i)
#pragma unroll
    for (int j = 0; j < 4; ++j) {
      const int cb = n0 + wn + 16 * j;  // lane-uniform
      const int col = cb + l16;
      const float b = bias[col];
#pragma unroll
      for (int r = 0; r < 4; ++r) {
        const int row = m0 + wm + 16 * i + quad * 4 + r;
        const float v = acc[i][j][r] + b;
        if (MODE == 0) {
          Cout[(size_t)row * DMODEL + col] = v;
        } else {
          if (cb < DHEAD)
            k16[(size_t)row * DHEAD + col] = f2h(v);
          else if (cb < 2 * DHEAD)
            vT[(size_t)(col - DHEAD) * S_LEN + row] = f2h(v);
          else
            q16[(size_t)row * DMODEL + (col - 2 * DHEAD)] = f2h(v * 8.0f);
        }
      }
    }
#undef LOADS
#undef STORES
#undef MFMAS
}

// ---------------------------------------------------------------- MFMA flash attention (f16) — unchanged from r3
#define QT 8
#define PSTR 208

__global__ __launch_bounds__(256)
void attn_kernel(const ushort* __restrict__ k16, const ushort* __restrict__ vT,
                 const ushort* __restrict__ q16, ushort* __restrict__ obuf) {
  __shared__ __align__(16) ushort lds[128 * PSTR + 64 * PSTR];
  ushort* Ksw = lds;
  ushort* P   = lds;
  ushort* Vt  = lds + 128 * PSTR;

  const int t = threadIdx.x;
  const int i0 = blockIdx.x * QT;
  const int jbase = (i0 >= WIN - 1) ? ((i0 - (WIN - 1)) & ~7) : 0;
  const int w = t >> 6, lane = t & 63;
  const int quad = lane >> 4, l16 = lane & 15;

#pragma unroll
  for (int i = 0; i < 6; ++i) {
    const int n = 6 * w + i;
    const int r = 8 * n + (lane >> 3);
    const int cs = (lane & 7) ^ (r & 7);
    async16(k16 + (size_t)(jbase + r) * DHEAD + cs * 8, &Ksw[n * 512]);
  }
  {
    const int d = t >> 2, p = t & 3;
#pragma unroll
    for (int it = 0; it < 6; ++it) {
      const int c = p + 4 * it;
      const uint4 raw = *(const uint4*)(vT + (size_t)d * S_LEN + jbase + c * 8);
      *(uint4*)(&Vt[d * PSTR + c * 8]) = raw;
    }
  }
  f16x8 qf[2][2];
#pragma unroll
  for (int tt = 0; tt < 2; ++tt) {
    const size_t qbase = (size_t)(i0 + 2 * w + tt) * DMODEL + l16 * DHEAD;
#pragma unroll
    for (int kst = 0; kst < 2; ++kst)
      qf[tt][kst] = *(const f16x8*)(q16 + qbase + kst * 32 + quad * 8);
  }
  __syncthreads();

  f32x4 acc[2][12] = {};
#pragma unroll
  for (int nt = 0; nt < 12; ++nt) {
#pragma unroll
    for (int kst = 0; kst < 2; ++kst) {
      const int cp = ((kst << 2) | quad) ^ (l16 & 7);
      const f16x8 bf = *(const f16x8*)(&Ksw[(nt * 16 + l16) * 64 + cp * 8]);
      acc[0][nt] = __builtin_amdgcn_mfma_f32_16x16x32_f16(qf[0][kst], bf, acc[0][nt], 0, 0, 0);
      acc[1][nt] = __builtin_amdgcn_mfma_f32_16x16x32_f16(qf[1][kst], bf, acc[1][nt], 0, 0, 0);
    }
  }
  __syncthreads();

  float inv_l[2][4];
#pragma unroll
  for (int tt = 0; tt < 2; ++tt) {
    const int qg = i0 + 2 * w + tt;
#pragma unroll
    for (int nt = 0; nt < 12; ++nt) {
      const int jg = jbase + nt * 16 + l16;
      const bool valid = (jg <= qg) && (jg > qg - WIN);
#pragma unroll
      for (int r = 0; r < 4; ++r)
        if (!valid) acc[tt][nt][r] = -1e30f;
    }
#pragma unroll
    for (int r = 0; r < 4; ++r) {
      float m = acc[tt][0][r];
#pragma unroll
      for (int nt = 1; nt < 12; ++nt) m = fmaxf(m, acc[tt][nt][r]);
#pragma unroll
      for (int off = 1; off < 16; off <<= 1) m = fmaxf(m, __shfl_xor(m, off));
      float s = 0.f;
#pragma unroll
      for (int nt = 0; nt < 12; ++nt) {
        const float e = __expf(acc[tt][nt][r] - m);
        acc[tt][nt][r] = e;
        s += e;
      }
#pragma unroll
      for (int off = 1; off < 16; off <<= 1) s += __shfl_xor(s, off);
      inv_l[tt][r] = 1.0f / s;
    }
    const int mrow0 = (2 * w + tt) * 16 + quad * 4;
#pragma unroll
    for (int r = 0; r < 4; ++r)
#pragma unroll
      for (int nt = 0; nt < 12; ++nt)
        P[(mrow0 + r) * PSTR + nt * 16 + l16] = f2h(acc[tt][nt][r]);
  }
  __syncthreads();

  f32x4 o[2][4] = {};
#pragma unroll
  for (int kst = 0; kst < 6; ++kst) {
    const f16x8 a0 = *(const f16x8*)(&P[((2 * w + 0) * 16 + l16) * PSTR + kst * 32 + quad * 8]);
    const f16x8 a1 = *(const f16x8*)(&P[((2 * w + 1) * 16 + l16) * PSTR + kst * 32 + quad * 8]);
#pragma unroll
    for (int nd = 0; nd < 4; ++nd) {
      const f16x8 b = *(const f16x8*)(&Vt[(nd * 16 + l16) * PSTR + kst * 32 + quad * 8]);
      o[0][nd] = __builtin_amdgcn_mfma_f32_16x16x32_f16(a0, b, o[0][nd], 0, 0, 0);
      o[1][nd] = __builtin_amdgcn_mfma_f32_16x16x32_f16(a1, b, o[1][nd], 0, 0, 0);
    }
  }

#pragma unroll
  for (int tt = 0; tt < 2; ++tt) {
    const size_t obase = (size_t)(i0 + 2 * w + tt) * DMODEL;
#pragma unroll
    for (int nd = 0; nd < 4; ++nd)
#pragma unroll
      for (int r = 0; r < 4; ++r) {
        const int col = (quad * 4 + r) * DHEAD + nd * 16 + l16;
        obuf[obase + col] = f2h(o[tt][nd][r] * inv_l[tt][r]);
      }
  }
}

// ---------------------------------------------------------------- launch
extern "C" void kernel_launch(void* const* d_in, const int* in_sizes, int n_in,
                              void* d_out, int out_size, void* d_ws, size_t ws_size,
                              hipStream_t stream) {
  const float* x    = (const float*)d_in[0];
  const float* Wqkv = (const float*)d_in[1];
  const float* bqkv = (const float*)d_in[2];
  const float* Wout = (const float*)d_in[3];
  const float* bout = (const float*)d_in[4];
  float* out = (float*)d_out;

  char* w = (char*)d_ws;
  ushort* wo16 = (ushort*)(w + 0);          // 2,097,152 B
  ushort* k16  = (ushort*)(w + 2097152);    //   270,336 B (2112 rows x 64)
  ushort* vT   = (ushort*)(w + 2367488);    //   270,336 B (64 x 2048 + slack)
  ushort* q16  = (ushort*)(w + 2637824);    // 4,194,304 B
  ushort* obuf = (ushort*)(w + 6832128);    // 4,194,304 B   (total ~11 MB)

  // gemm1 (288 tile-blocks: 32 M x 9 N) + Wout convert (64 blocks)
  gemm_fused<1><<<288 + 64, 256, 0, stream>>>(
      x, Wqkv, nullptr, nullptr, bqkv, nullptr, k16, vT, q16, Wout, wo16, 288);

  attn_kernel<<<S_LEN / QT, 256, 0, stream>>>(k16, vT, q16, obuf);

  // gemm2 (256 tile-blocks: 32 M x 8 N)
  gemm_fused<0><<<256, 256, 0, stream>>>(
      nullptr, nullptr, obuf, wo16, bout, out, nullptr, nullptr, nullptr, nullptr, nullptr, 999);
}